// Round 7
// baseline (7665.376 us; speedup 1.0000x reference)
//
#include <hip/hip_runtime.h>
#include <hip/hip_bf16.h>
#include <cstdint>
#include <cstddef>

#define T_STEPS 256
#define BATCH   128
#define VOCAB   256
#define EDIM    512
#define NH      1024
#define GDIM    4096   // 4*NH
#define NST0    40     // layer0 k-steps: 8 (x) + 32 (h)
#define NST1    64     // layer1 k-steps: 32 (h0) + 32 (h1)

typedef __attribute__((ext_vector_type(8))) short short8;
typedef __attribute__((ext_vector_type(4))) float floatx4;

__device__ __forceinline__ float sigmoidf_(float x) { return 1.0f / (1.0f + __expf(-x)); }
__device__ __forceinline__ float tanhf_(float x)    { return 1.0f - 2.0f / (__expf(2.0f * x) + 1.0f); }

typedef __attribute__((address_space(1))) const unsigned int guint;
typedef __attribute__((address_space(3))) unsigned int luint;
__device__ __forceinline__ void load_lds16(const void* g, void* l) {
    __builtin_amdgcn_global_load_lds((guint*)g, (luint*)l, 16, 0, 0);
}

// ---------------- fp32 GEMM (prep only: Wcomb = emb @ W0x) ----------------
#define BM 128
#define BN 128
#define BK 16
__global__ __launch_bounds__(256) void sgemm_f32(
    const float* __restrict__ A, const float* __restrict__ B,
    float* __restrict__ C, int M, int N, int K)
{
    __shared__ float As[BK][BM + 4];
    __shared__ float Bs[BK][BN + 4];
    const int tid = threadIdx.x;
    const int tr = tid >> 4, tc = tid & 15;
    const int bm = blockIdx.y, bn = blockIdx.x;
    const float* Ab = A + (size_t)bm * BM * K;
    float acc[8][8];
    #pragma unroll
    for (int i = 0; i < 8; ++i)
        #pragma unroll
        for (int j = 0; j < 8; ++j) acc[i][j] = 0.f;
    for (int k0 = 0; k0 < K; k0 += BK) {
        #pragma unroll
        for (int l = 0; l < 2; ++l) {
            int idx = tid + l * 256;
            int row = idx >> 2, c4 = idx & 3;
            float4 v = *(const float4*)(Ab + (size_t)row * K + k0 + c4 * 4);
            As[c4 * 4 + 0][row] = v.x; As[c4 * 4 + 1][row] = v.y;
            As[c4 * 4 + 2][row] = v.z; As[c4 * 4 + 3][row] = v.w;
        }
        #pragma unroll
        for (int l = 0; l < 2; ++l) {
            int idx = tid + l * 256;
            int row = idx >> 5, c4 = idx & 31;
            *(float4*)&Bs[row][c4 * 4] = *(const float4*)(B + (size_t)(k0 + row) * N + bn * BN + c4 * 4);
        }
        __syncthreads();
        #pragma unroll
        for (int kk = 0; kk < BK; ++kk) {
            float4 a0 = *(const float4*)&As[kk][tr * 8];
            float4 a1 = *(const float4*)&As[kk][tr * 8 + 4];
            float4 b0 = *(const float4*)&Bs[kk][tc * 8];
            float4 b1 = *(const float4*)&Bs[kk][tc * 8 + 4];
            float av[8] = {a0.x, a0.y, a0.z, a0.w, a1.x, a1.y, a1.z, a1.w};
            float bv[8] = {b0.x, b0.y, b0.z, b0.w, b1.x, b1.y, b1.z, b1.w};
            #pragma unroll
            for (int i = 0; i < 8; ++i)
                #pragma unroll
                for (int j = 0; j < 8; ++j) acc[i][j] += av[i] * bv[j];
        }
        __syncthreads();
    }
    #pragma unroll
    for (int i = 0; i < 8; ++i) {
        size_t row = (size_t)bm * BM + tr * 8 + i;
        #pragma unroll
        for (int j = 0; j < 8; j += 4) {
            int col = bn * BN + tc * 8 + j;
            *(float4*)(C + row * N + col) =
                make_float4(acc[i][j], acc[i][j+1], acc[i][j+2], acc[i][j+3]);
        }
    }
}

// ---------------- transpose + fp32->bf16 ----------------
__global__ __launch_bounds__(256) void transpose_to_bf16(
    const float* __restrict__ src, __hip_bfloat16* __restrict__ dst, int R, int C)
{
    __shared__ float t[32][33];
    int x = blockIdx.x * 32 + threadIdx.x;
    #pragma unroll
    for (int i = 0; i < 4; ++i) {
        int y = blockIdx.y * 32 + threadIdx.y + i * 8;
        t[threadIdx.y + i * 8][threadIdx.x] = src[(size_t)y * C + x];
    }
    __syncthreads();
    int x2 = blockIdx.y * 32 + threadIdx.x;
    #pragma unroll
    for (int i = 0; i < 4; ++i) {
        int y2 = blockIdx.x * 32 + threadIdx.y + i * 8;
        dst[(size_t)y2 * R + x2] = __float2bfloat16(t[threadIdx.x][threadIdx.y + i * 8]);
    }
}

// ------- pack (fallback 8-col 2-tile format) -------
__global__ __launch_bounds__(256) void pack_w2(
    const float* __restrict__ src, __hip_bfloat16* __restrict__ dst,
    int koff, int NSTEPS)
{
    __shared__ float t[64][33];
    const int tid = threadIdx.x;
    const int xt = blockIdx.x;
    const int kt = blockIdx.y;
    {
        int yl = tid >> 3;
        int x0 = (tid & 7) * 8;
        const float* p = src + (size_t)(kt * 32 + yl) * GDIM + xt * 64 + x0;
        float4 v0 = *(const float4*)p;
        float4 v1 = *(const float4*)(p + 4);
        t[x0 + 0][yl] = v0.x; t[x0 + 1][yl] = v0.y; t[x0 + 2][yl] = v0.z; t[x0 + 3][yl] = v0.w;
        t[x0 + 4][yl] = v1.x; t[x0 + 5][yl] = v1.y; t[x0 + 6][yl] = v1.z; t[x0 + 7][yl] = v1.w;
    }
    __syncthreads();
    {
        int ll = tid >> 2;
        int quad = tid & 3;
        int lincol = xt * 64 + ll;
        int g = lincol >> 10, n = lincol & 1023;
        int j = n >> 3, c = n & 7;
        int tt = g >> 1;
        int l16 = (g & 1) * 8 + c;
        int s = (koff >> 5) + kt;
        __hip_bfloat16 o[8];
        #pragma unroll
        for (int jj = 0; jj < 8; ++jj)
            o[jj] = __float2bfloat16(t[ll][quad * 8 + jj]);
        size_t off = ((((size_t)j * NSTEPS + s) * 2 + tt) * 64 + (size_t)quad * 16 + l16) * 8;
        *(uint4*)(dst + off) = *(const uint4*)o;
    }
}

// ------- pack (fused 4-col single-tile format) -------
// Block j (0..255) owns 4 hidden cols. One 1KB fragment per k-step s:
// layout [quad][l16][8]: elem jj -> src row koff + s*32 + quad*8 + jj,
// src col (l16>>2)*NH + j*4 + (l16&3)   (l16 = gate*4 + c).
// So fragment offset = ((j*NSTEPS + s)*64 + quad*16 + l16)*8.
__global__ __launch_bounds__(256) void pack_w4(
    const float* __restrict__ src, __hip_bfloat16* __restrict__ dst,
    int koff, int NSTEPS)
{
    __shared__ float t[64][33];
    const int tid = threadIdx.x;
    const int xt = blockIdx.x;   // lincol tile of 64
    const int kt = blockIdx.y;   // k tile of 32
    {
        int yl = tid >> 3;
        int x0 = (tid & 7) * 8;
        const float* p = src + (size_t)(kt * 32 + yl) * GDIM + xt * 64 + x0;
        float4 v0 = *(const float4*)p;
        float4 v1 = *(const float4*)(p + 4);
        t[x0 + 0][yl] = v0.x; t[x0 + 1][yl] = v0.y; t[x0 + 2][yl] = v0.z; t[x0 + 3][yl] = v0.w;
        t[x0 + 4][yl] = v1.x; t[x0 + 5][yl] = v1.y; t[x0 + 6][yl] = v1.z; t[x0 + 7][yl] = v1.w;
    }
    __syncthreads();
    {
        int ll = tid >> 2;
        int quad = tid & 3;
        int lincol = xt * 64 + ll;
        int g = lincol >> 10, n = lincol & 1023;
        int j = n >> 2;            // block (4 cols each)
        int l16 = g * 4 + (n & 3); // gate*4 + c
        int s = (koff >> 5) + kt;
        __hip_bfloat16 o[8];
        #pragma unroll
        for (int jj = 0; jj < 8; ++jj)
            o[jj] = __float2bfloat16(t[ll][quad * 8 + jj]);
        size_t off = (((size_t)j * NSTEPS + s) * 64 + (size_t)quad * 16 + l16) * 8;
        *(uint4*)(dst + off) = *(const uint4*)o;
    }
}

// ---------------- fp32 -> bf16 convert ----------------
__global__ __launch_bounds__(256) void convert_to_bf16(
    const float* __restrict__ src, __hip_bfloat16* __restrict__ dst, size_t n4)
{
    size_t i = (size_t)blockIdx.x * 256 + threadIdx.x;
    if (i < n4) {
        float4 v = *(const float4*)(src + i * 4);
        __hip_bfloat16 o[4] = {__float2bfloat16(v.x), __float2bfloat16(v.y),
                               __float2bfloat16(v.z), __float2bfloat16(v.w)};
        *(uint2*)(dst + i * 4) = *(uint2*)o;
    }
}

// ---------------- bf16 MFMA GEMM (output layer) ----------------
#define GKP 40
__global__ __launch_bounds__(256) void gemm_bt(
    const __hip_bfloat16* __restrict__ A, const __hip_bfloat16* __restrict__ Bt,
    const float* __restrict__ bias, float* __restrict__ C, int M, int N, int K)
{
    __shared__ __hip_bfloat16 As[128 * GKP];
    __shared__ __hip_bfloat16 Bs[128 * GKP];
    const int tid = threadIdx.x;
    const int wave = tid >> 6, lane = tid & 63;
    const int quad = lane >> 4, l16 = lane & 15;
    const int wm = (wave >> 1) * 64, wn = (wave & 1) * 64;
    const size_t Arow0 = (size_t)blockIdx.y * 128;
    const size_t Brow0 = (size_t)blockIdx.x * 128;
    floatx4 acc[4][4];
    #pragma unroll
    for (int i = 0; i < 4; ++i)
        #pragma unroll
        for (int j = 0; j < 4; ++j) acc[i][j] = (floatx4)0.f;

    for (int k0 = 0; k0 < K; k0 += 32) {
        #pragma unroll
        for (int l = 0; l < 2; ++l) {
            int idx = tid + l * 256;
            int row = idx >> 2, seg = idx & 3;
            *(uint4*)(As + row * GKP + seg * 8) =
                *(const uint4*)(A + (Arow0 + row) * K + k0 + seg * 8);
            *(uint4*)(Bs + row * GKP + seg * 8) =
                *(const uint4*)(Bt + (Brow0 + row) * K + k0 + seg * 8);
        }
        __syncthreads();
        short8 af[4], bf[4];
        #pragma unroll
        for (int i = 0; i < 4; ++i)
            af[i] = *(const short8*)(As + (wm + i * 16 + l16) * GKP + quad * 8);
        #pragma unroll
        for (int j = 0; j < 4; ++j)
            bf[j] = *(const short8*)(Bs + (wn + j * 16 + l16) * GKP + quad * 8);
        #pragma unroll
        for (int i = 0; i < 4; ++i)
            #pragma unroll
            for (int j = 0; j < 4; ++j)
                acc[i][j] = __builtin_amdgcn_mfma_f32_16x16x32_bf16(af[i], bf[j], acc[i][j], 0, 0, 0);
        __syncthreads();
    }
    #pragma unroll
    for (int i = 0; i < 4; ++i)
        #pragma unroll
        for (int j = 0; j < 4; ++j) {
            int col = (int)Brow0 + wn + j * 16 + l16;
            float bv = bias ? bias[col] : 0.f;
            #pragma unroll
            for (int r = 0; r < 4; ++r) {
                size_t row = Arow0 + wm + i * 16 + quad * 4 + r;
                C[row * N + col] = acc[i][j][r] + bv;
            }
        }
}

// ---- chunk engines: depth-3 A-register pipeline, static indexing only ----
struct AfBuf { short8 a[3][8]; };

template<int NCF, int NCS>
__device__ __forceinline__ void chunks_pro(
    AfBuf& B, const __hip_bfloat16* __restrict__ pF,
    const __hip_bfloat16* __restrict__ pS)
{
    constexpr int NC = NCF + NCS;
    constexpr int D = (NC < 3) ? NC : 3;
    #pragma unroll
    for (int c = 0; c < D; ++c) {
        const __hip_bfloat16* pa = (c < NCF) ? (pF + (size_t)c * 256)
                                             : (pS + (size_t)(c - NCF) * 256);
        #pragma unroll
        for (int ss = 0; ss < 8; ++ss)
            B.a[c][ss] = *(const short8*)(pa + ss * 32);
    }
}

// two-tile (fallback 8-col format)
template<int NCF, int NCS, int WF, int WS>
__device__ __forceinline__ void chunks_main(
    AfBuf& B, const __hip_bfloat16* __restrict__ pF,
    const __hip_bfloat16* __restrict__ pS,
    const __hip_bfloat16* Wlds, int lane,
    floatx4& acc0, floatx4& acc1)
{
    constexpr int NC = NCF + NCS;
    #pragma unroll
    for (int c = 0; c < NC; ++c) {
        const int wc = (c < NCF) ? (WF + c) : (WS + (c - NCF));
        #pragma unroll
        for (int ss = 0; ss < 8; ++ss) {
            const int s = wc * 8 + ss;
            short8 bf0 = *(const short8*)&Wlds[s * 1024 + lane * 8];
            short8 bf1 = *(const short8*)&Wlds[s * 1024 + 512 + lane * 8];
            acc0 = __builtin_amdgcn_mfma_f32_16x16x32_bf16(B.a[c % 3][ss], bf0, acc0, 0, 0, 0);
            acc1 = __builtin_amdgcn_mfma_f32_16x16x32_bf16(B.a[c % 3][ss], bf1, acc1, 0, 0, 0);
        }
        if (c + 3 < NC) {
            const int cn = c + 3;
            const __hip_bfloat16* pa = (cn < NCF) ? (pF + (size_t)cn * 256)
                                                  : (pS + (size_t)(cn - NCF) * 256);
            #pragma unroll
            for (int ss = 0; ss < 8; ++ss)
                B.a[cn % 3][ss] = *(const short8*)(pa + ss * 32);
        }
    }
}

// single-tile (fused 4-col format)
template<int NCF, int NCS, int WF, int WS>
__device__ __forceinline__ void chunks1_main(
    AfBuf& B, const __hip_bfloat16* __restrict__ pF,
    const __hip_bfloat16* __restrict__ pS,
    const __hip_bfloat16* Wlds, int lane,
    floatx4& acc)
{
    constexpr int NC = NCF + NCS;
    #pragma unroll
    for (int c = 0; c < NC; ++c) {
        const int wc = (c < NCF) ? (WF + c) : (WS + (c - NCF));
        #pragma unroll
        for (int ss = 0; ss < 8; ++ss) {
            const int s = wc * 8 + ss;
            short8 bf = *(const short8*)&Wlds[s * 512 + lane * 8];
            acc = __builtin_amdgcn_mfma_f32_16x16x32_bf16(B.a[c % 3][ss], bf, acc, 0, 0, 0);
        }
        if (c + 3 < NC) {
            const int cn = c + 3;
            const __hip_bfloat16* pa = (cn < NCF) ? (pF + (size_t)cn * 256)
                                                  : (pS + (size_t)(cn - NCF) * 256);
            #pragma unroll
            for (int ss = 0; ss < 8; ++ss)
                B.a[cn % 3][ss] = *(const short8*)(pa + ss * 32);
        }
    }
}

// ---------------- diagonal fused LSTM step (fallback path, 8-col fmt) ----------------
__global__ __launch_bounds__(512) void lstm_diag(
    const __hip_bfloat16* __restrict__ inbf,
    const __hip_bfloat16* __restrict__ Wpack0,
    const __hip_bfloat16* __restrict__ Wpack1,
    const float* __restrict__ b0, const float* __restrict__ b1,
    __hip_bfloat16* __restrict__ h0_cur,
    const __hip_bfloat16* __restrict__ h0_prev,
    float* __restrict__ c0, float* __restrict__ c1,
    __hip_bfloat16* __restrict__ H1all,
    int d)
{
    const int bid = blockIdx.x;
    const int layer = (bid >> 3) & 1;
    const int j = ((bid >> 4) << 3) | (bid & 7);
    if (layer == 0 && d >= T_STEPS) return;
    if (layer == 1 && d == 0) return;

    __shared__ __attribute__((aligned(16))) __hip_bfloat16 Wlds[65536];

    const int tid = threadIdx.x;
    const int wave = tid >> 6, lane = tid & 63;
    const int quad = lane >> 4, l16 = lane & 15;

    const __hip_bfloat16 *A0, *A1;
    int A0stride;
    const float* bb; float* cst; __hip_bfloat16* hout;
    bool first;
    if (layer == 0) {
        first = (d == 0);
        bb = b0; cst = c0;
        A0 = inbf + (size_t)d * (BATCH * VOCAB); A0stride = VOCAB;
        A1 = h0_prev;
        hout = h0_cur;
        const __hip_bfloat16* Wp = Wpack0 + (size_t)j * (NST0 * 1024);
        #pragma unroll
        for (int it = 0; it < 10; ++it)
            load_lds16(Wp + it * 4096 + tid * 8, Wlds + it * 4096 + tid * 8);
    } else {
        first = (d == 1);
        bb = b1; cst = c1;
        A0 = h0_prev; A0stride = NH;
        A1 = (d >= 2) ? (H1all + (size_t)(d - 2) * (BATCH * NH)) : h0_prev;
        hout = H1all + (size_t)(d - 1) * (BATCH * NH);
        const __hip_bfloat16* Wp = Wpack1 + (size_t)j * (NST1 * 1024);
        #pragma unroll
        for (int it = 0; it < 16; ++it)
            load_lds16(Wp + it * 4096 + tid * 8, Wlds + it * 4096 + tid * 8);
    }

    const int row = wave * 16 + l16;
    const __hip_bfloat16* pA0 = A0 + (size_t)row * A0stride + quad * 8;
    const __hip_bfloat16* pA1 = A1 + (size_t)row * NH + quad * 8;

    const int cc = j * 8 + (l16 & 7);
    float bv0 = bb[((l16 < 8) ? 0 : 1) * NH + cc];
    float bv1 = bb[((l16 < 8) ? 2 : 3) * NH + cc];
    float cold[4];
    {
        const int bbase = 16 * wave + quad * 4;
        #pragma unroll
        for (int r = 0; r < 4; ++r)
            cold[r] = first ? 0.f : cst[(size_t)(bbase + r) * NH + cc];
    }
    floatx4 acc0 = {bv0, bv0, bv0, bv0};
    floatx4 acc1 = {bv1, bv1, bv1, bv1};

    AfBuf B;
    __syncthreads();
    if (layer == 0) {
        if (first) { chunks_pro<1, 0>(B, pA0, pA0); chunks_main<1, 0, 0, 0>(B, pA0, pA0, Wlds, lane, acc0, acc1); }
        else       { chunks_pro<1, 4>(B, pA0, pA1); chunks_main<1, 4, 0, 1>(B, pA0, pA1, Wlds, lane, acc0, acc1); }
    } else {
        if (first) { chunks_pro<4, 0>(B, pA0, pA0); chunks_main<4, 0, 0, 0>(B, pA0, pA0, Wlds, lane, acc0, acc1); }
        else       { chunks_pro<4, 4>(B, pA1, pA0); chunks_main<4, 4, 4, 0>(B, pA1, pA0, Wlds, lane, acc0, acc1); }
    }

    #pragma unroll
    for (int r = 0; r < 4; ++r) {
        float a0 = acc0[r], a1 = acc1[r];
        float p0 = __shfl_xor(a0, 8, 64);
        float p1 = __shfl_xor(a1, 8, 64);
        if (l16 < 8) {
            int b = 16 * wave + quad * 4 + r;
            float f  = sigmoidf_(a0);
            float ig = sigmoidf_(p0);
            float oo = sigmoidf_(a1);
            float gg = tanhf_(p1);
            size_t idx = (size_t)b * NH + cc;
            float cn = f * cold[r] + ig * gg;
            float hn = oo * tanhf_(cn);
            cst[idx] = cn;
            hout[idx] = __float2bfloat16(hn);
        }
    }
}

// ---------------- distributed epoch sync (no RMW, no fences) ----------------
__device__ __forceinline__ void spin_all_ge256(const uint32_t* ep, uint32_t target,
                                               int lane, int wave) {
    asm volatile("" ::: "memory");
    if (wave == 0) {
        for (;;) {
            uint32_t a = __hip_atomic_load(&ep[lane],       __ATOMIC_RELAXED, __HIP_MEMORY_SCOPE_AGENT);
            uint32_t b = __hip_atomic_load(&ep[lane + 64],  __ATOMIC_RELAXED, __HIP_MEMORY_SCOPE_AGENT);
            uint32_t c = __hip_atomic_load(&ep[lane + 128], __ATOMIC_RELAXED, __HIP_MEMORY_SCOPE_AGENT);
            uint32_t d = __hip_atomic_load(&ep[lane + 192], __ATOMIC_RELAXED, __HIP_MEMORY_SCOPE_AGENT);
            if (__all(a >= target && b >= target && c >= target && d >= target)) break;
            __builtin_amdgcn_s_sleep(2);
        }
    }
    __builtin_amdgcn_s_barrier();
    asm volatile("" ::: "memory");
}

__device__ __forceinline__ void arrive_ep(uint32_t* slot, uint32_t val) {
    __syncthreads();   // each wave drains vmcnt: sc1 h-stores device-visible
    asm volatile("" ::: "memory");
    if (threadIdx.x == 0)
        __hip_atomic_store(slot, val, __ATOMIC_RELAXED, __HIP_MEMORY_SCOPE_AGENT);
}

__global__ void zero_bar(uint32_t* p) { p[threadIdx.x] = 0; }

// ---------------- persistent fused-layer LSTM (v5) ----------------
// 256 blocks (1/CU), block j owns 4 cols of layer-0 AND 4 cols of layer-1.
// LDS: W0 40KB + W1 64KB = 104KB, loaded once (4-col single-tile fragments:
// l16 = gate*4 + c). Superstep e: h0[e] = lstm0(x[e], h0[e-1]);
// h1[e-1] = lstm1(h0[e-1], h1[e-2]). Both depend only on superstep e-1 ->
// ONE all-to-all sync per superstep (257 total). c-state in registers
// (lanes l16<4). h-exchange: sc1 write-once panels H0all/H1all; the L1-phase
// h0 reads hit L1/L2 (same addresses as L0 phase).
__global__ __launch_bounds__(512) void lstm_persist5(
    const __hip_bfloat16* __restrict__ inbf,
    const __hip_bfloat16* __restrict__ Wp0,    // [256][40][1KB] 4-col fmt
    const __hip_bfloat16* __restrict__ Wp1,    // [256][64][1KB] 4-col fmt
    const float* __restrict__ b0, const float* __restrict__ b1,
    __hip_bfloat16* __restrict__ H0all,        // [256][128][1024]
    __hip_bfloat16* __restrict__ H1all,        // [256][128][1024]
    uint32_t* __restrict__ ep)                 // [256]
{
    __shared__ __attribute__((aligned(16))) __hip_bfloat16 W0lds[NST0 * 512]; // 40 KB
    __shared__ __attribute__((aligned(16))) __hip_bfloat16 W1lds[NST1 * 512]; // 64 KB

    const int j = blockIdx.x;
    const int tid = threadIdx.x;
    const int wave = tid >> 6, lane = tid & 63;
    const int quad = lane >> 4, l16 = lane & 15;

    // ---- one-time: weights -> LDS ----
    {
        const __hip_bfloat16* W0p = Wp0 + (size_t)j * (NST0 * 512);
        #pragma unroll
        for (int it = 0; it < 5; ++it)
            load_lds16(W0p + it * 4096 + tid * 8, W0lds + it * 4096 + tid * 8);
        const __hip_bfloat16* W1p = Wp1 + (size_t)j * (NST1 * 512);
        #pragma unroll
        for (int it = 0; it < 8; ++it)
            load_lds16(W1p + it * 4096 + tid * 8, W1lds + it * 4096 + tid * 8);
    }
    __syncthreads();

    const int gate = l16 >> 2, c4 = l16 & 3;
    const int cc = j * 4 + c4;                 // hidden col (valid l16<4 owner)
    const float bv0 = b0[gate * NH + j * 4 + c4];
    const float bv1 = b1[gate * NH + j * 4 + c4];
    const int row = wave * 16 + l16;
    float creg0[4] = {0.f, 0.f, 0.f, 0.f};
    float creg1[4] = {0.f, 0.f, 0.f, 0.f};

    for (int e = 0; e <= T_STEPS; ++e) {
        if (e) spin_all_ge256(ep, (uint32_t)e, lane, wave);

        // ---------- layer-0 phase: h0[e] ----------
        if (e < T_STEPS) {
            const bool first = (e == 0);
            const __hip_bfloat16* pX =
                inbf + (size_t)e * (BATCH * VOCAB) + (size_t)row * VOCAB + quad * 8;
            const __hip_bfloat16* pH0 = first ? pX :
                (H0all + (size_t)(e - 1) * (BATCH * NH) + (size_t)row * NH + quad * 8);
            __hip_bfloat16* hout = H0all + (size_t)e * (BATCH * NH);
            floatx4 acc = {bv0, bv0, bv0, bv0};
            AfBuf B;
            if (first) {
                chunks_pro<1, 0>(B, pX, pX);
                chunks1_main<1, 0, 0, 0>(B, pX, pX, W0lds, lane, acc);
            } else {
                chunks_pro<1, 4>(B, pX, pH0);
                chunks1_main<1, 4, 0, 1>(B, pX, pH0, W0lds, lane, acc);
            }
            #pragma unroll
            for (int r = 0; r < 4; ++r) {
                float v0  = acc[r];
                float v4  = __shfl_xor(v0, 4, 64);
                float v8  = __shfl_xor(v0, 8, 64);
                float v12 = __shfl_xor(v4, 8, 64);
                float f  = sigmoidf_(v0);
                float ig = sigmoidf_(v4);
                float oo = sigmoidf_(v8);
                float gg = tanhf_(v12);
                float cn = f * (first ? 0.f : creg0[r]) + ig * gg;
                if (l16 < 4) creg0[r] = cn;
                float hn = oo * tanhf_(cn);
                union { __hip_bfloat16 h; unsigned short u; } cv;
                cv.h = __float2bfloat16(hn);
                unsigned int other = __shfl_xor((unsigned int)cv.u, 1, 64);
                if (l16 < 4 && !(l16 & 1)) {
                    unsigned int packed = (unsigned int)cv.u | (other << 16);
                    int b = 16 * wave + quad * 4 + r;
                    __hip_atomic_store((unsigned int*)&hout[(size_t)b * NH + cc],
                                       packed, __ATOMIC_RELAXED, __HIP_MEMORY_SCOPE_AGENT);
                }
            }
        }

        // ---------- layer-1 phase: h1[e-1] ----------
        if (e >= 1) {
            const bool first = (e == 1);
            const __hip_bfloat16* pH0 =
                H0all + (size_t)(e - 1) * (BATCH * NH) + (size_t)row * NH + quad * 8;
            const __hip_bfloat16* pH1 = first ? pH0 :
                (H1all + (size_t)(e - 2) * (BATCH * NH) + (size_t)row * NH + quad * 8);
            __hip_bfloat16* hout = H1all + (size_t)(e - 1) * (BATCH * NH);
            floatx4 acc = {bv1, bv1, bv1, bv1};
            AfBuf B;
            if (first) {
                chunks_pro<4, 0>(B, pH0, pH0);
                chunks1_main<4, 0, 0, 0>(B, pH0, pH0, W1lds, lane, acc);
            } else {
                chunks_pro<4, 4>(B, pH0, pH1);
                chunks1_main<4, 4, 0, 4>(B, pH0, pH1, W1lds, lane, acc);
            }
            #pragma unroll
            for (int r = 0; r < 4; ++r) {
                float v0  = acc[r];
                float v4  = __shfl_xor(v0, 4, 64);
                float v8  = __shfl_xor(v0, 8, 64);
                float v12 = __shfl_xor(v4, 8, 64);
                float f  = sigmoidf_(v0);
                float ig = sigmoidf_(v4);
                float oo = sigmoidf_(v8);
                float gg = tanhf_(v12);
                float cn = f * (first ? 0.f : creg1[r]) + ig * gg;
                if (l16 < 4) creg1[r] = cn;
                float hn = oo * tanhf_(cn);
                union { __hip_bfloat16 h; unsigned short u; } cv;
                cv.h = __float2bfloat16(hn);
                unsigned int other = __shfl_xor((unsigned int)cv.u, 1, 64);
                if (l16 < 4 && !(l16 & 1)) {
                    unsigned int packed = (unsigned int)cv.u | (other << 16);
                    int b = 16 * wave + quad * 4 + r;
                    __hip_atomic_store((unsigned int*)&hout[(size_t)b * NH + cc],
                                       packed, __ATOMIC_RELAXED, __HIP_MEMORY_SCOPE_AGENT);
                }
            }
        }

        arrive_ep(&ep[j], (uint32_t)(e + 1));
    }
}

extern "C" void kernel_launch(void* const* d_in, const int* in_sizes, int n_in,
                              void* d_out, int out_size, void* d_ws, size_t ws_size,
                              hipStream_t stream)
{
    const float* inputs = (const float*)d_in[0];  // [256,128,256]
    const float* emb    = (const float*)d_in[1];  // [256,512]
    const float* w0     = (const float*)d_in[2];  // [1536,4096]
    const float* b0     = (const float*)d_in[3];  // [4096]
    const float* w1     = (const float*)d_in[4];  // [2048,4096]
    const float* b1     = (const float*)d_in[5];  // [4096]
    const float* outw   = (const float*)d_in[6];  // [1024,256]
    const float* outb   = (const float*)d_in[7];  // [256]
    float* out = (float*)d_out;                   // [32768,256]

    char* ws = (char*)d_ws;
    size_t off = 0;
    auto take = [&](size_t bytes) { char* p = ws + off; off += (bytes + 255) & ~(size_t)255; return p; };
    float* Wcomb = (float*)take((size_t)VOCAB * GDIM * 4);                          // 4 MB
    __hip_bfloat16* Wpack0 = (__hip_bfloat16*)take((size_t)128 * NST0 * 1024 * 2);  // 10 MB (fallback fmt)
    __hip_bfloat16* Wpack1 = (__hip_bfloat16*)take((size_t)128 * NST1 * 1024 * 2);  // 16 MB (fallback fmt)
    __hip_bfloat16* outwt  = (__hip_bfloat16*)take((size_t)NH * VOCAB * 2);         // 0.5 MB
    __hip_bfloat16* inbf   = (__hip_bfloat16*)take((size_t)T_STEPS * BATCH * VOCAB * 2); // 16 MB
    __hip_bfloat16* h0pp0  = (__hip_bfloat16*)take((size_t)BATCH * NH * 2);
    __hip_bfloat16* h0pp1  = (__hip_bfloat16*)take((size_t)BATCH * NH * 2);
    float* c0 = (float*)take((size_t)BATCH * NH * 4);
    float* c1 = (float*)take((size_t)BATCH * NH * 4);
    uint32_t* bar = (uint32_t*)take(1024);
    __hip_bfloat16* H1all  = (__hip_bfloat16*)take((size_t)T_STEPS * BATCH * NH * 2); // 64 MB
    __hip_bfloat16* H0all  = (__hip_bfloat16*)take((size_t)T_STEPS * BATCH * NH * 2); // 64 MB
    __hip_bfloat16* Wp0n   = (__hip_bfloat16*)take((size_t)256 * NST0 * 512 * 2);   // 10 MB (4-col fmt)
    __hip_bfloat16* Wp1n   = (__hip_bfloat16*)take((size_t)256 * NST1 * 512 * 2);   // 16 MB (4-col fmt)
    const bool ws_ok = (off <= ws_size);

    // ---- prep ----
    sgemm_f32<<<dim3(GDIM / BN, VOCAB / BM), 256, 0, stream>>>(
        emb, w0, Wcomb, VOCAB, GDIM, EDIM);
    // fallback packs (8-col 2-tile)
    pack_w2<<<dim3(64, VOCAB / 32), 256, 0, stream>>>(Wcomb, Wpack0, 0, NST0);
    pack_w2<<<dim3(64, NH / 32), 256, 0, stream>>>(w0 + (size_t)EDIM * GDIM, Wpack0, VOCAB, NST0);
    pack_w2<<<dim3(64, NH / 32), 256, 0, stream>>>(w1, Wpack1, 0, NST1);
    pack_w2<<<dim3(64, NH / 32), 256, 0, stream>>>(w1 + (size_t)NH * GDIM, Wpack1, NH, NST1);
    if (ws_ok) {
        // fused packs (4-col single-tile)
        pack_w4<<<dim3(64, VOCAB / 32), 256, 0, stream>>>(Wcomb, Wp0n, 0, NST0);
        pack_w4<<<dim3(64, NH / 32), 256, 0, stream>>>(w0 + (size_t)EDIM * GDIM, Wp0n, VOCAB, NST0);
        pack_w4<<<dim3(64, NH / 32), 256, 0, stream>>>(w1, Wp1n, 0, NST1);
        pack_w4<<<dim3(64, NH / 32), 256, 0, stream>>>(w1 + (size_t)NH * GDIM, Wp1n, NH, NST1);
    }
    transpose_to_bf16<<<dim3(VOCAB / 32, NH / 32), dim3(32, 8), 0, stream>>>(
        outw, outwt, NH, VOCAB);
    {
        size_t n4 = (size_t)T_STEPS * BATCH * VOCAB / 4;
        convert_to_bf16<<<(int)((n4 + 255) / 256), 256, 0, stream>>>(inputs, inbf, n4);
    }
    zero_bar<<<1, 256, 0, stream>>>(bar);

    // ---- recurrence ----
    bool done = false;
    if (ws_ok) {
        void* args[] = { (void*)&inbf, (void*)&Wp0n, (void*)&Wp1n,
                         (void*)&b0, (void*)&b1,
                         (void*)&H0all, (void*)&H1all, (void*)&bar };
        hipError_t ce = hipLaunchCooperativeKernel(lstm_persist5, dim3(256), dim3(512),
                                                   args, 0u, stream);
        done = (ce == hipSuccess);
    }
    if (!done) {
        for (int d = 0; d <= T_STEPS; ++d) {
            __hip_bfloat16* hcur = (d & 1) ? h0pp1 : h0pp0;
            __hip_bfloat16* hprev = (d & 1) ? h0pp0 : h0pp1;
            lstm_diag<<<256, 512, 0, stream>>>(
                inbf, Wpack0, Wpack1, b0, b1, hcur, hprev, c0, c1, H1all, d);
        }
    }

    // ---- logits = H1 @ out_w + out_b ----
    gemm_bt<<<dim3(VOCAB / 128, (T_STEPS * BATCH) / 128), 256, 0, stream>>>(
        H1all, outwt, outb, out, T_STEPS * BATCH, VOCAB, NH);
}

// Round 8
// 4787.756 us; speedup vs baseline: 1.6010x; 1.6010x over previous
//
#include <hip/hip_runtime.h>
#include <hip/hip_bf16.h>
#include <cstdint>
#include <cstddef>

#define T_STEPS 256
#define BATCH   128
#define VOCAB   256
#define EDIM    512
#define NH      1024
#define GDIM    4096   // 4*NH
#define NST0    40     // layer0 k-steps: 8 (x) + 32 (h)
#define NST1    64     // layer1 k-steps: 32 (h0) + 32 (h1)

typedef __attribute__((ext_vector_type(8))) short short8;
typedef __attribute__((ext_vector_type(4))) float floatx4;

__device__ __forceinline__ float sigmoidf_(float x) { return 1.0f / (1.0f + __expf(-x)); }
__device__ __forceinline__ float tanhf_(float x)    { return 1.0f - 2.0f / (__expf(2.0f * x) + 1.0f); }

typedef __attribute__((address_space(1))) const unsigned int guint;
typedef __attribute__((address_space(3))) unsigned int luint;
__device__ __forceinline__ void load_lds16(const void* g, void* l) {
    __builtin_amdgcn_global_load_lds((guint*)g, (luint*)l, 16, 0, 0);
}

// ---------------- fp32 GEMM (prep only: Wcomb = emb @ W0x) ----------------
#define BM 128
#define BN 128
#define BK 16
__global__ __launch_bounds__(256) void sgemm_f32(
    const float* __restrict__ A, const float* __restrict__ B,
    float* __restrict__ C, int M, int N, int K)
{
    __shared__ float As[BK][BM + 4];
    __shared__ float Bs[BK][BN + 4];
    const int tid = threadIdx.x;
    const int tr = tid >> 4, tc = tid & 15;
    const int bm = blockIdx.y, bn = blockIdx.x;
    const float* Ab = A + (size_t)bm * BM * K;
    float acc[8][8];
    #pragma unroll
    for (int i = 0; i < 8; ++i)
        #pragma unroll
        for (int j = 0; j < 8; ++j) acc[i][j] = 0.f;
    for (int k0 = 0; k0 < K; k0 += BK) {
        #pragma unroll
        for (int l = 0; l < 2; ++l) {
            int idx = tid + l * 256;
            int row = idx >> 2, c4 = idx & 3;
            float4 v = *(const float4*)(Ab + (size_t)row * K + k0 + c4 * 4);
            As[c4 * 4 + 0][row] = v.x; As[c4 * 4 + 1][row] = v.y;
            As[c4 * 4 + 2][row] = v.z; As[c4 * 4 + 3][row] = v.w;
        }
        #pragma unroll
        for (int l = 0; l < 2; ++l) {
            int idx = tid + l * 256;
            int row = idx >> 5, c4 = idx & 31;
            *(float4*)&Bs[row][c4 * 4] = *(const float4*)(B + (size_t)(k0 + row) * N + bn * BN + c4 * 4);
        }
        __syncthreads();
        #pragma unroll
        for (int kk = 0; kk < BK; ++kk) {
            float4 a0 = *(const float4*)&As[kk][tr * 8];
            float4 a1 = *(const float4*)&As[kk][tr * 8 + 4];
            float4 b0 = *(const float4*)&Bs[kk][tc * 8];
            float4 b1 = *(const float4*)&Bs[kk][tc * 8 + 4];
            float av[8] = {a0.x, a0.y, a0.z, a0.w, a1.x, a1.y, a1.z, a1.w};
            float bv[8] = {b0.x, b0.y, b0.z, b0.w, b1.x, b1.y, b1.z, b1.w};
            #pragma unroll
            for (int i = 0; i < 8; ++i)
                #pragma unroll
                for (int j = 0; j < 8; ++j) acc[i][j] += av[i] * bv[j];
        }
        __syncthreads();
    }
    #pragma unroll
    for (int i = 0; i < 8; ++i) {
        size_t row = (size_t)bm * BM + tr * 8 + i;
        #pragma unroll
        for (int j = 0; j < 8; j += 4) {
            int col = bn * BN + tc * 8 + j;
            *(float4*)(C + row * N + col) =
                make_float4(acc[i][j], acc[i][j+1], acc[i][j+2], acc[i][j+3]);
        }
    }
}

// ---------------- transpose + fp32->bf16 ----------------
__global__ __launch_bounds__(256) void transpose_to_bf16(
    const float* __restrict__ src, __hip_bfloat16* __restrict__ dst, int R, int C)
{
    __shared__ float t[32][33];
    int x = blockIdx.x * 32 + threadIdx.x;
    #pragma unroll
    for (int i = 0; i < 4; ++i) {
        int y = blockIdx.y * 32 + threadIdx.y + i * 8;
        t[threadIdx.y + i * 8][threadIdx.x] = src[(size_t)y * C + x];
    }
    __syncthreads();
    int x2 = blockIdx.y * 32 + threadIdx.x;
    #pragma unroll
    for (int i = 0; i < 4; ++i) {
        int y2 = blockIdx.x * 32 + threadIdx.y + i * 8;
        dst[(size_t)y2 * R + x2] = __float2bfloat16(t[threadIdx.x][threadIdx.y + i * 8]);
    }
}

// ------- pack weights: per-(block j, k-step s, n-tile t) 1KB fragments -------
// elem_off = ((((j*NSTEPS + s)*2 + t)*64 + quad*16 + l16)*8 + jj
__global__ __launch_bounds__(256) void pack_w2(
    const float* __restrict__ src, __hip_bfloat16* __restrict__ dst,
    int koff, int NSTEPS)
{
    __shared__ float t[64][33];
    const int tid = threadIdx.x;
    const int xt = blockIdx.x;
    const int kt = blockIdx.y;
    {
        int yl = tid >> 3;
        int x0 = (tid & 7) * 8;
        const float* p = src + (size_t)(kt * 32 + yl) * GDIM + xt * 64 + x0;
        float4 v0 = *(const float4*)p;
        float4 v1 = *(const float4*)(p + 4);
        t[x0 + 0][yl] = v0.x; t[x0 + 1][yl] = v0.y; t[x0 + 2][yl] = v0.z; t[x0 + 3][yl] = v0.w;
        t[x0 + 4][yl] = v1.x; t[x0 + 5][yl] = v1.y; t[x0 + 6][yl] = v1.z; t[x0 + 7][yl] = v1.w;
    }
    __syncthreads();
    {
        int ll = tid >> 2;
        int quad = tid & 3;
        int lincol = xt * 64 + ll;
        int g = lincol >> 10, n = lincol & 1023;
        int j = n >> 3, c = n & 7;
        int tt = g >> 1;
        int l16 = (g & 1) * 8 + c;
        int s = (koff >> 5) + kt;
        __hip_bfloat16 o[8];
        #pragma unroll
        for (int jj = 0; jj < 8; ++jj)
            o[jj] = __float2bfloat16(t[ll][quad * 8 + jj]);
        size_t off = ((((size_t)j * NSTEPS + s) * 2 + tt) * 64 + (size_t)quad * 16 + l16) * 8;
        *(uint4*)(dst + off) = *(const uint4*)o;
    }
}

// ---------------- fp32 -> bf16 convert ----------------
__global__ __launch_bounds__(256) void convert_to_bf16(
    const float* __restrict__ src, __hip_bfloat16* __restrict__ dst, size_t n4)
{
    size_t i = (size_t)blockIdx.x * 256 + threadIdx.x;
    if (i < n4) {
        float4 v = *(const float4*)(src + i * 4);
        __hip_bfloat16 o[4] = {__float2bfloat16(v.x), __float2bfloat16(v.y),
                               __float2bfloat16(v.z), __float2bfloat16(v.w)};
        *(uint2*)(dst + i * 4) = *(uint2*)o;
    }
}

// ---------------- bf16 MFMA GEMM (output layer) ----------------
#define GKP 40
__global__ __launch_bounds__(256) void gemm_bt(
    const __hip_bfloat16* __restrict__ A, const __hip_bfloat16* __restrict__ Bt,
    const float* __restrict__ bias, float* __restrict__ C, int M, int N, int K)
{
    __shared__ __hip_bfloat16 As[128 * GKP];
    __shared__ __hip_bfloat16 Bs[128 * GKP];
    const int tid = threadIdx.x;
    const int wave = tid >> 6, lane = tid & 63;
    const int quad = lane >> 4, l16 = lane & 15;
    const int wm = (wave >> 1) * 64, wn = (wave & 1) * 64;
    const size_t Arow0 = (size_t)blockIdx.y * 128;
    const size_t Brow0 = (size_t)blockIdx.x * 128;
    floatx4 acc[4][4];
    #pragma unroll
    for (int i = 0; i < 4; ++i)
        #pragma unroll
        for (int j = 0; j < 4; ++j) acc[i][j] = (floatx4)0.f;

    for (int k0 = 0; k0 < K; k0 += 32) {
        #pragma unroll
        for (int l = 0; l < 2; ++l) {
            int idx = tid + l * 256;
            int row = idx >> 2, seg = idx & 3;
            *(uint4*)(As + row * GKP + seg * 8) =
                *(const uint4*)(A + (Arow0 + row) * K + k0 + seg * 8);
            *(uint4*)(Bs + row * GKP + seg * 8) =
                *(const uint4*)(Bt + (Brow0 + row) * K + k0 + seg * 8);
        }
        __syncthreads();
        short8 af[4], bf[4];
        #pragma unroll
        for (int i = 0; i < 4; ++i)
            af[i] = *(const short8*)(As + (wm + i * 16 + l16) * GKP + quad * 8);
        #pragma unroll
        for (int j = 0; j < 4; ++j)
            bf[j] = *(const short8*)(Bs + (wn + j * 16 + l16) * GKP + quad * 8);
        #pragma unroll
        for (int i = 0; i < 4; ++i)
            #pragma unroll
            for (int j = 0; j < 4; ++j)
                acc[i][j] = __builtin_amdgcn_mfma_f32_16x16x32_bf16(af[i], bf[j], acc[i][j], 0, 0, 0);
        __syncthreads();
    }
    #pragma unroll
    for (int i = 0; i < 4; ++i)
        #pragma unroll
        for (int j = 0; j < 4; ++j) {
            int col = (int)Brow0 + wn + j * 16 + l16;
            float bv = bias ? bias[col] : 0.f;
            #pragma unroll
            for (int r = 0; r < 4; ++r) {
                size_t row = Arow0 + wm + i * 16 + quad * 4 + r;
                C[row * N + col] = acc[i][j][r] + bv;
            }
        }
}

// ---- single-panel segment: prologue (3 chunks' A-loads) + compute with
// rolling depth-3 prefetch. NC chunks from pA, weight chunks W..W+NC-1.
// 8-col 2-tile format. Static indexing only.
template<int NC, int W>
__device__ __forceinline__ void seg_run(
    const __hip_bfloat16* __restrict__ pA,
    const __hip_bfloat16* Wlds, int lane,
    floatx4& acc0, floatx4& acc1)
{
    constexpr int D = (NC < 3) ? NC : 3;
    short8 af[3][8];
    #pragma unroll
    for (int c = 0; c < D; ++c)
        #pragma unroll
        for (int ss = 0; ss < 8; ++ss)
            af[c][ss] = *(const short8*)(pA + (size_t)c * 256 + ss * 32);
    #pragma unroll
    for (int c = 0; c < NC; ++c) {
        #pragma unroll
        for (int ss = 0; ss < 8; ++ss) {
            const int s = (W + c) * 8 + ss;
            short8 bf0 = *(const short8*)&Wlds[s * 1024 + lane * 8];
            short8 bf1 = *(const short8*)&Wlds[s * 1024 + 512 + lane * 8];
            acc0 = __builtin_amdgcn_mfma_f32_16x16x32_bf16(af[c % 3][ss], bf0, acc0, 0, 0, 0);
            acc1 = __builtin_amdgcn_mfma_f32_16x16x32_bf16(af[c % 3][ss], bf1, acc1, 0, 0, 0);
        }
        if (c + 3 < NC) {
            #pragma unroll
            for (int ss = 0; ss < 8; ++ss)
                af[(c + 3) % 3][ss] = *(const short8*)(pA + (size_t)(c + 3) * 256 + ss * 32);
        }
    }
}

// ---------------- diagonal fused LSTM step (fallback path) ----------------
__global__ __launch_bounds__(512) void lstm_diag(
    const __hip_bfloat16* __restrict__ inbf,
    const __hip_bfloat16* __restrict__ Wpack0,
    const __hip_bfloat16* __restrict__ Wpack1,
    const float* __restrict__ b0, const float* __restrict__ b1,
    __hip_bfloat16* __restrict__ h0_cur,
    const __hip_bfloat16* __restrict__ h0_prev,
    float* __restrict__ c0, float* __restrict__ c1,
    __hip_bfloat16* __restrict__ H1all,
    int d)
{
    const int bid = blockIdx.x;
    const int layer = (bid >> 3) & 1;
    const int j = ((bid >> 4) << 3) | (bid & 7);
    if (layer == 0 && d >= T_STEPS) return;
    if (layer == 1 && d == 0) return;

    __shared__ __attribute__((aligned(16))) __hip_bfloat16 Wlds[65536];

    const int tid = threadIdx.x;
    const int wave = tid >> 6, lane = tid & 63;
    const int quad = lane >> 4, l16 = lane & 15;

    const __hip_bfloat16 *A0, *A1;
    int A0stride;
    const float* bb; float* cst; __hip_bfloat16* hout;
    bool first;
    if (layer == 0) {
        first = (d == 0);
        bb = b0; cst = c0;
        A0 = inbf + (size_t)d * (BATCH * VOCAB); A0stride = VOCAB;
        A1 = h0_prev;
        hout = h0_cur;
        const __hip_bfloat16* Wp = Wpack0 + (size_t)j * (NST0 * 1024);
        #pragma unroll
        for (int it = 0; it < 10; ++it)
            load_lds16(Wp + it * 4096 + tid * 8, Wlds + it * 4096 + tid * 8);
    } else {
        first = (d == 1);
        bb = b1; cst = c1;
        A0 = h0_prev; A0stride = NH;
        A1 = (d >= 2) ? (H1all + (size_t)(d - 2) * (BATCH * NH)) : h0_prev;
        hout = H1all + (size_t)(d - 1) * (BATCH * NH);
        const __hip_bfloat16* Wp = Wpack1 + (size_t)j * (NST1 * 1024);
        #pragma unroll
        for (int it = 0; it < 16; ++it)
            load_lds16(Wp + it * 4096 + tid * 8, Wlds + it * 4096 + tid * 8);
    }

    const int row = wave * 16 + l16;
    const __hip_bfloat16* pA0 = A0 + (size_t)row * A0stride + quad * 8;
    const __hip_bfloat16* pA1 = A1 + (size_t)row * NH + quad * 8;

    const int cc = j * 8 + (l16 & 7);
    float bv0 = bb[((l16 < 8) ? 0 : 1) * NH + cc];
    float bv1 = bb[((l16 < 8) ? 2 : 3) * NH + cc];
    float cold[4];
    {
        const int bbase = 16 * wave + quad * 4;
        #pragma unroll
        for (int r = 0; r < 4; ++r)
            cold[r] = first ? 0.f : cst[(size_t)(bbase + r) * NH + cc];
    }
    floatx4 acc0 = {bv0, bv0, bv0, bv0};
    floatx4 acc1 = {bv1, bv1, bv1, bv1};

    __syncthreads();   // drain weight staging
    if (layer == 0) {
        seg_run<1, 0>(pA0, Wlds, lane, acc0, acc1);
        if (!first) seg_run<4, 1>(pA1, Wlds, lane, acc0, acc1);
    } else {
        if (first) {
            seg_run<4, 0>(pA0, Wlds, lane, acc0, acc1);
        } else {
            seg_run<4, 4>(pA1, Wlds, lane, acc0, acc1);
            seg_run<4, 0>(pA0, Wlds, lane, acc0, acc1);
        }
    }

    #pragma unroll
    for (int r = 0; r < 4; ++r) {
        float a0 = acc0[r], a1 = acc1[r];
        float p0 = __shfl_xor(a0, 8, 64);
        float p1 = __shfl_xor(a1, 8, 64);
        if (l16 < 8) {
            int b = 16 * wave + quad * 4 + r;
            float f  = sigmoidf_(a0);
            float ig = sigmoidf_(p0);
            float oo = sigmoidf_(a1);
            float gg = tanhf_(p1);
            size_t idx = (size_t)b * NH + cc;
            float cn = f * cold[r] + ig * gg;
            float hn = oo * tanhf_(cn);
            cst[idx] = cn;
            hout[idx] = __float2bfloat16(hn);
        }
    }
}

// ---------------- distributed epoch sync (no RMW, no fences) ----------------
// Arrival: one sc1 store of completed-step count to ep[j]. Wait: wave 0
// gathers 128 slots with 2 coalesced agent-scope lane-loads + __all, then
// releases via raw s_barrier (no vmcnt drain -> prefetches stay in flight).
__device__ __forceinline__ void spin_all_ge(const uint32_t* ep, uint32_t target,
                                            int lane, int wave) {
    asm volatile("" ::: "memory");
    if (wave == 0) {
        for (;;) {
            uint32_t a = __hip_atomic_load(&ep[lane], __ATOMIC_RELAXED, __HIP_MEMORY_SCOPE_AGENT);
            uint32_t b = __hip_atomic_load(&ep[lane + 64], __ATOMIC_RELAXED, __HIP_MEMORY_SCOPE_AGENT);
            if (__all(a >= target && b >= target)) break;
            __builtin_amdgcn_s_sleep(1);
        }
    }
    __builtin_amdgcn_s_barrier();
    asm volatile("" ::: "memory");
}

__device__ __forceinline__ void arrive_ep(uint32_t* slot, uint32_t val) {
    __syncthreads();   // each wave drains vmcnt: sc1 h-stores device-visible
    asm volatile("" ::: "memory");
    if (threadIdx.x == 0)
        __hip_atomic_store(slot, val, __ATOMIC_RELAXED, __HIP_MEMORY_SCOPE_AGENT);
}

__global__ void zero_bar(uint32_t* p) { p[threadIdx.x] = 0; }

// ---- epilogue: compute gates, update c-regs, pack 8 cols -> 2x8B sc1 stores ----
__device__ __forceinline__ void epilogue_store(
    floatx4 acc0, floatx4 acc1, float* creg, bool first,
    int wave, int quad, int l16, int cc8base,
    __hip_bfloat16* __restrict__ hout)
{
    #pragma unroll
    for (int r = 0; r < 4; ++r) {
        float a0 = acc0[r], a1 = acc1[r];
        float p0 = __shfl_xor(a0, 8, 64);
        float p1 = __shfl_xor(a1, 8, 64);
        float f  = sigmoidf_(a0);
        float ig = sigmoidf_(p0);
        float oo = sigmoidf_(a1);
        float gg = tanhf_(p1);
        float cn = f * (first ? 0.f : creg[r]) + ig * gg;
        if (l16 < 8) creg[r] = cn;
        float hn = oo * tanhf_(cn);
        union { __hip_bfloat16 h; unsigned short u; } cv;
        cv.h = __float2bfloat16(hn);
        // pack 8 lanes (l16 0..7) -> 2 lanes (l16 0,4) of 8B each
        unsigned int v1 = (unsigned int)cv.u |
                          (__shfl_xor((unsigned int)cv.u, 1, 64) << 16); // cols l16,l16+1 on even l16
        unsigned int v2 = __shfl_xor(v1, 2, 64);                         // cols l16+2,l16+3
        unsigned long long p8 = (unsigned long long)v1 |
                                ((unsigned long long)v2 << 32);          // cols l16..l16+3 on l16 in {0,4}
        if (l16 == 0 || l16 == 4) {
            int b = 16 * wave + quad * 4 + r;
            __hip_atomic_store((unsigned long long*)&hout[(size_t)b * NH + cc8base + l16],
                               p8, __ATOMIC_RELAXED, __HIP_MEMORY_SCOPE_AGENT);
        }
    }
}

// ---------------- persistent LSTM v6: layer-decoupled + compute-over-wait ----
// 256 blocks (1/CU), XCD-balanced: layer=(bid>>3)&1, j=((bid>>4)<<3)|(bid&7).
// Weights in LDS once; c-state in registers; h-exchange via write-once sc1
// arrays H0all/H1all (plain consumer loads can't be stale).
// Key ordering: each step's dependency waits are INTERLEAVED with compute --
//  L0: [x-chunk compute] -> spin(ep0>=d) -> [4 h0-chunks]
//  L1: spin(ep1>=d-1) -> [4 h1-chunks] -> spin(ep0>=d) -> [4 h0-chunks]
// so the cross-layer hop (ep0 post + HBM refetch) hides under ~3.5us of MFMA.
__global__ __launch_bounds__(512) void lstm_persist6(
    const __hip_bfloat16* __restrict__ inbf,
    const __hip_bfloat16* __restrict__ Wpack0,
    const __hip_bfloat16* __restrict__ Wpack1,
    const float* __restrict__ b0, const float* __restrict__ b1,
    __hip_bfloat16* __restrict__ H0all,        // [256][128][1024]
    __hip_bfloat16* __restrict__ H1all,        // [256][128][1024]
    uint32_t* __restrict__ bar)                // [0..127]=ep0, [128..255]=ep1
{
    __shared__ __attribute__((aligned(16))) __hip_bfloat16 Wlds[65536]; // 128 KB

    const int bid = blockIdx.x;
    const int layer = (bid >> 3) & 1;
    const int j = ((bid >> 4) << 3) | (bid & 7);
    const int tid = threadIdx.x;
    const int wave = tid >> 6, lane = tid & 63;
    const int quad = lane >> 4, l16 = lane & 15;

    uint32_t* ep0 = bar;
    uint32_t* ep1 = bar + 128;

    // ---- one-time: weights -> LDS ----
    if (layer == 0) {
        const __hip_bfloat16* Wp = Wpack0 + (size_t)j * (NST0 * 1024);
        #pragma unroll
        for (int it = 0; it < 10; ++it)
            load_lds16(Wp + it * 4096 + tid * 8, Wlds + it * 4096 + tid * 8);
    } else {
        const __hip_bfloat16* Wp = Wpack1 + (size_t)j * (NST1 * 1024);
        #pragma unroll
        for (int it = 0; it < 16; ++it)
            load_lds16(Wp + it * 4096 + tid * 8, Wlds + it * 4096 + tid * 8);
    }
    __syncthreads();

    const int cc = j * 8 + (l16 & 7);
    const float* bb = layer ? b1 : b0;
    const float bv0 = bb[((l16 < 8) ? 0 : 1) * NH + cc];
    const float bv1 = bb[((l16 < 8) ? 2 : 3) * NH + cc];
    const int row = wave * 16 + l16;
    float creg[4] = {0.f, 0.f, 0.f, 0.f};

    if (layer == 0) {
        // ---------- layer-0 chain ----------
        for (int d = 0; d < T_STEPS; ++d) {
            const bool first = (d == 0);
            const __hip_bfloat16* pX =
                inbf + (size_t)d * (BATCH * VOCAB) + (size_t)row * VOCAB + quad * 8;
            __hip_bfloat16* hout = H0all + (size_t)d * (BATCH * NH);
            floatx4 acc0 = {bv0, bv0, bv0, bv0};
            floatx4 acc1 = {bv1, bv1, bv1, bv1};
            // x-chunk needs no dependency: compute it BEFORE the epoch wait
            seg_run<1, 0>(pX, Wlds, lane, acc0, acc1);
            if (!first) {
                spin_all_ge(ep0, (uint32_t)d, lane, wave);   // h0[d-1] complete
                const __hip_bfloat16* pH0 =
                    H0all + (size_t)(d - 1) * (BATCH * NH) + (size_t)row * NH + quad * 8;
                seg_run<4, 1>(pH0, Wlds, lane, acc0, acc1);
            }
            epilogue_store(acc0, acc1, creg, first, wave, quad, l16, j * 8, hout);
            arrive_ep(&ep0[j], (uint32_t)(d + 1));
        }
    } else {
        // ---------- layer-1 chain ----------
        for (int d = 1; d <= T_STEPS; ++d) {
            const bool first = (d == 1);
            __hip_bfloat16* hout = H1all + (size_t)(d - 1) * (BATCH * NH);
            floatx4 acc0 = {bv0, bv0, bv0, bv0};
            floatx4 acc1 = {bv1, bv1, bv1, bv1};
            if (!first) {
                // h1 half first: needs only the L1 epoch
                spin_all_ge(ep1, (uint32_t)(d - 1), lane, wave);  // h1[d-2] done
                const __hip_bfloat16* pH1 =
                    H1all + (size_t)(d - 2) * (BATCH * NH) + (size_t)row * NH + quad * 8;
                seg_run<4, 4>(pH1, Wlds, lane, acc0, acc1);
            }
            // cross-layer wait: by now ep0[d] is usually already posted
            spin_all_ge(ep0, (uint32_t)d, lane, wave);            // h0[d-1] done
            const __hip_bfloat16* pH0 =
                H0all + (size_t)(d - 1) * (BATCH * NH) + (size_t)row * NH + quad * 8;
            seg_run<4, 0>(pH0, Wlds, lane, acc0, acc1);
            epilogue_store(acc0, acc1, creg, first, wave, quad, l16, j * 8, hout);
            arrive_ep(&ep1[j], (uint32_t)d);
        }
    }
}

extern "C" void kernel_launch(void* const* d_in, const int* in_sizes, int n_in,
                              void* d_out, int out_size, void* d_ws, size_t ws_size,
                              hipStream_t stream)
{
    const float* inputs = (const float*)d_in[0];  // [256,128,256]
    const float* emb    = (const float*)d_in[1];  // [256,512]
    const float* w0     = (const float*)d_in[2];  // [1536,4096]
    const float* b0     = (const float*)d_in[3];  // [4096]
    const float* w1     = (const float*)d_in[4];  // [2048,4096]
    const float* b1     = (const float*)d_in[5];  // [4096]
    const float* outw   = (const float*)d_in[6];  // [1024,256]
    const float* outb   = (const float*)d_in[7];  // [256]
    float* out = (float*)d_out;                   // [32768,256]

    char* ws = (char*)d_ws;
    size_t off = 0;
    auto take = [&](size_t bytes) { char* p = ws + off; off += (bytes + 255) & ~(size_t)255; return p; };
    float* Wcomb = (float*)take((size_t)VOCAB * GDIM * 4);                          // 4 MB
    __hip_bfloat16* Wpack0 = (__hip_bfloat16*)take((size_t)128 * NST0 * 1024 * 2);  // 10 MB
    __hip_bfloat16* Wpack1 = (__hip_bfloat16*)take((size_t)128 * NST1 * 1024 * 2);  // 16 MB
    __hip_bfloat16* outwt  = (__hip_bfloat16*)take((size_t)NH * VOCAB * 2);         // 0.5 MB
    __hip_bfloat16* inbf   = (__hip_bfloat16*)take((size_t)T_STEPS * BATCH * VOCAB * 2); // 16 MB
    __hip_bfloat16* h0pp0  = (__hip_bfloat16*)take((size_t)BATCH * NH * 2);
    __hip_bfloat16* h0pp1  = (__hip_bfloat16*)take((size_t)BATCH * NH * 2);
    float* c0 = (float*)take((size_t)BATCH * NH * 4);
    float* c1 = (float*)take((size_t)BATCH * NH * 4);
    uint32_t* bar = (uint32_t*)take(1024);
    __hip_bfloat16* H1all  = (__hip_bfloat16*)take((size_t)T_STEPS * BATCH * NH * 2); // 64 MB
    __hip_bfloat16* H0all  = (__hip_bfloat16*)take((size_t)T_STEPS * BATCH * NH * 2); // 64 MB
    const bool ws_ok = (off <= ws_size);

    // ---- prep ----
    sgemm_f32<<<dim3(GDIM / BN, VOCAB / BM), 256, 0, stream>>>(
        emb, w0, Wcomb, VOCAB, GDIM, EDIM);
    pack_w2<<<dim3(64, VOCAB / 32), 256, 0, stream>>>(Wcomb, Wpack0, 0, NST0);
    pack_w2<<<dim3(64, NH / 32), 256, 0, stream>>>(w0 + (size_t)EDIM * GDIM, Wpack0, VOCAB, NST0);
    pack_w2<<<dim3(64, NH / 32), 256, 0, stream>>>(w1, Wpack1, 0, NST1);
    pack_w2<<<dim3(64, NH / 32), 256, 0, stream>>>(w1 + (size_t)NH * GDIM, Wpack1, NH, NST1);
    transpose_to_bf16<<<dim3(VOCAB / 32, NH / 32), dim3(32, 8), 0, stream>>>(
        outw, outwt, NH, VOCAB);
    {
        size_t n4 = (size_t)T_STEPS * BATCH * VOCAB / 4;
        convert_to_bf16<<<(int)((n4 + 255) / 256), 256, 0, stream>>>(inputs, inbf, n4);
    }
    zero_bar<<<1, 256, 0, stream>>>(bar);

    // ---- recurrence ----
    bool done = false;
    if (ws_ok) {
        void* args[] = { (void*)&inbf, (void*)&Wpack0, (void*)&Wpack1,
                         (void*)&b0, (void*)&b1,
                         (void*)&H0all, (void*)&H1all, (void*)&bar };
        hipError_t ce = hipLaunchCooperativeKernel(lstm_persist6, dim3(256), dim3(512),
                                                   args, 0u, stream);
        done = (ce == hipSuccess);
    }
    if (!done) {
        for (int d = 0; d <= T_STEPS; ++d) {
            __hip_bfloat16* hcur = (d & 1) ? h0pp1 : h0pp0;
            __hip_bfloat16* hprev = (d & 1) ? h0pp0 : h0pp1;
            lstm_diag<<<256, 512, 0, stream>>>(
                inbf, Wpack0, Wpack1, b0, b1, hcur, hprev, c0, c1, H1all, d);
        }
    }

    // ---- logits = H1 @ out_w + out_b ----
    gemm_bt<<<dim3(VOCAB / 128, (T_STEPS * BATCH) / 128), 256, 0, stream>>>(
        H1all, outwt, outb, out, T_STEPS * BATCH, VOCAB, NH);
}